// Round 1
// baseline (2048.305 us; speedup 1.0000x reference)
//
#include <hip/hip_runtime.h>
#include <math.h>

// Problem constants
#define T      2048
#define HIDDEN 2048
#define NH     32
#define NKV    4
#define D      128
#define WINDOW 512
#define QKVW   ((NH + 2 * NKV) * D)   // 5120
#define ODIM   (NH * D)               // 4096
#define EPS    1e-6f
#define SCALE  0.08838834764831845f   // D^-0.5
#define NEGINF (-1.0e30f)

// ---------------------------------------------------------------------------
// Kernel 1/5: fp32 tiled GEMM  C[M,N] = A[M,K] * B[K,N]
// 128x128 tile, BK=8, 256 threads, 8x8 per thread, float4 LDS paths.
// M,N,K must be multiples of 128/128/8 (true for all our shapes).
// ---------------------------------------------------------------------------
__global__ __launch_bounds__(256)
void gemm_f32(const float* __restrict__ A, const float* __restrict__ B,
              float* __restrict__ C, int M, int N, int K) {
  constexpr int BM = 128, BN = 128, BK = 8;
  __shared__ float As[BK][BM + 4];   // row stride 132 floats = 528B (16B-aligned)
  __shared__ float Bs[BK][BN + 4];

  const int tid = threadIdx.x;
  const int m0 = blockIdx.y * BM;
  const int n0 = blockIdx.x * BN;

  // A staging: each thread loads one float4 (row am, cols ak..ak+3), stores transposed
  const int am = tid >> 1;          // 0..127
  const int ak = (tid & 1) * 4;     // 0 or 4
  // B staging: each thread loads one float4 (row bk, cols bn..bn+3)
  const int bk = tid >> 5;          // 0..7
  const int bn = (tid & 31) * 4;    // 0..124

  const int ty = tid >> 4;          // 0..15 -> rows ty*8..+7
  const int tx = tid & 15;          // 0..15 -> cols tx*8..+7

  float acc[8][8];
#pragma unroll
  for (int i = 0; i < 8; ++i)
#pragma unroll
    for (int j = 0; j < 8; ++j) acc[i][j] = 0.f;

  const float* Aptr = A + (size_t)(m0 + am) * K + ak;
  const float* Bptr = B + (size_t)bk * N + n0 + bn;

  for (int k0 = 0; k0 < K; k0 += BK) {
    float4 av = *(const float4*)(Aptr + k0);
    float4 bv = *(const float4*)(Bptr + (size_t)k0 * N);
    As[ak + 0][am] = av.x;
    As[ak + 1][am] = av.y;
    As[ak + 2][am] = av.z;
    As[ak + 3][am] = av.w;
    *(float4*)&Bs[bk][bn] = bv;
    __syncthreads();

#pragma unroll
    for (int k = 0; k < BK; ++k) {
      float a[8], b[8];
      *(float4*)&a[0] = *(const float4*)&As[k][ty * 8];
      *(float4*)&a[4] = *(const float4*)&As[k][ty * 8 + 4];
      *(float4*)&b[0] = *(const float4*)&Bs[k][tx * 8];
      *(float4*)&b[4] = *(const float4*)&Bs[k][tx * 8 + 4];
#pragma unroll
      for (int i = 0; i < 8; ++i)
#pragma unroll
        for (int j = 0; j < 8; ++j) acc[i][j] = fmaf(a[i], b[j], acc[i][j]);
    }
    __syncthreads();
  }

#pragma unroll
  for (int i = 0; i < 8; ++i) {
    float* cp = C + (size_t)(m0 + ty * 8 + i) * N + n0 + tx * 8;
    *(float4*)cp       = make_float4(acc[i][0], acc[i][1], acc[i][2], acc[i][3]);
    *((float4*)cp + 1) = make_float4(acc[i][4], acc[i][5], acc[i][6], acc[i][7]);
  }
}

// ---------------------------------------------------------------------------
// Kernel 2/5: RoPE cos/sin tables, double-precision angle computation.
// grid(T), block(64): j = freq index.
// ---------------------------------------------------------------------------
__global__ __launch_bounds__(64)
void rope_tables(const int* __restrict__ positions,
                 float* __restrict__ cosT, float* __restrict__ sinT) {
  const int t = blockIdx.x;
  const int j = threadIdx.x;               // 0..63
  const double inv_freq = pow(1.0e6, -(double)j / 64.0);
  const double ang = (double)positions[t] * inv_freq;
  cosT[t * 64 + j] = (float)cos(ang);
  sinT[t * 64 + j] = (float)sin(ang);
}

// ---------------------------------------------------------------------------
// Kernel 3/5: fused RMSNorm + RoPE, in place on qkv.
// grid(T, NH+NKV), block(128). blockIdx.y < NH -> q head, else k head.
// ---------------------------------------------------------------------------
__global__ __launch_bounds__(128)
void norm_rope(float* __restrict__ qkv,
               const float* __restrict__ qw, const float* __restrict__ kw,
               const float* __restrict__ cosT, const float* __restrict__ sinT) {
  const int t = blockIdx.x;
  const int hh = blockIdx.y;
  const int d = threadIdx.x;               // 0..127

  float* x;
  const float* w;
  if (hh < NH) { x = qkv + (size_t)t * QKVW + hh * D;               w = qw; }
  else         { x = qkv + (size_t)t * QKVW + NH * D + (hh - NH) * D; w = kw; }

  const float v = x[d];
  float ss = v * v;
#pragma unroll
  for (int off = 32; off >= 1; off >>= 1) ss += __shfl_xor(ss, off);

  __shared__ float sred[2];
  if ((d & 63) == 0) sred[d >> 6] = ss;
  __syncthreads();
  const float total = sred[0] + sred[1];
  const float r = 1.0f / sqrtf(total * (1.0f / D) + EPS);
  const float nv = v * r * w[d];

  __shared__ float buf[D];
  buf[d] = nv;
  __syncthreads();

  const int j = d & 63;
  const float c = cosT[t * 64 + j];
  const float s = sinT[t * 64 + j];
  const float x1 = buf[j];
  const float x2 = buf[j + 64];
  x[d] = (d < 64) ? (x1 * c - x2 * s) : (x2 * c + x1 * s);
}

// ---------------------------------------------------------------------------
// Kernel 4/5: sliding-window causal attention, flash-style online softmax.
// grid(NH, T/64), block(256). 4 consecutive lanes per query row; each lane
// owns a 32-dim slice of q and o. 32-key K/V tiles staged in LDS.
// Masking uses -1e30 (no inf): while a query has seen no valid key, m stays
// NEGINF and garbage accumulates, but the first real key gives
// alpha = expf(NEGINF - m_real) = 0 which wipes o and l exactly.
// ---------------------------------------------------------------------------
__global__ __launch_bounds__(256)
void attn_swa(const float* __restrict__ qkv, float* __restrict__ out) {
  const int h = blockIdx.x;                 // q head
  const int q0 = blockIdx.y * 64;
  const int kvh = h >> 3;                   // h / (NH/NKV)
  const int tid = threadIdx.x;
  const int g = tid >> 2;                   // query within tile 0..63
  const int sub = tid & 3;                  // dim-slice 0..3
  const int qidx = q0 + g;

  __shared__ float Ks[32][D];               // 16 KB
  __shared__ float Vs[32][D];               // 16 KB

  float q[32], o[32];
  const float* qp = qkv + (size_t)qidx * QKVW + h * D + sub * 32;
#pragma unroll
  for (int i = 0; i < 32; i += 4) *(float4*)&q[i] = *(const float4*)(qp + i);
#pragma unroll
  for (int i = 0; i < 32; ++i) o[i] = 0.f;

  float m = NEGINF, l = 0.f;

  int kstart = q0 - (WINDOW - 1);
  if (kstart < 0) kstart = 0;
  kstart &= ~31;
  const int kend = q0 + 64;

  for (int kt = kstart; kt < kend; kt += 32) {
    __syncthreads();
    // stage K/V tile: 32 rows x 128 floats each; 256 threads x 4 float4s
#pragma unroll
    for (int i = tid * 4; i < 32 * D; i += 256 * 4) {
      const int kk = i >> 7;
      const int dd = i & 127;
      const float* base = qkv + (size_t)(kt + kk) * QKVW + NH * D + kvh * D + dd;
      *(float4*)&Ks[kk][dd] = *(const float4*)base;
      *(float4*)&Vs[kk][dd] = *(const float4*)(base + NKV * D);
    }
    __syncthreads();

    float s[32];
#pragma unroll
    for (int kk = 0; kk < 32; ++kk) {
      const float4* kp = (const float4*)&Ks[kk][sub * 32];
      float p = 0.f;
#pragma unroll
      for (int j = 0; j < 8; ++j) {
        const float4 kv = kp[j];
        p = fmaf(q[4 * j + 0], kv.x, p);
        p = fmaf(q[4 * j + 1], kv.y, p);
        p = fmaf(q[4 * j + 2], kv.z, p);
        p = fmaf(q[4 * j + 3], kv.w, p);
      }
      p += __shfl_xor(p, 1);
      p += __shfl_xor(p, 2);
      const int kidx = kt + kk;
      const bool valid = (kidx <= qidx) && (qidx - kidx < WINDOW);
      s[kk] = valid ? p * SCALE : NEGINF;
    }

    float mt = m;
#pragma unroll
    for (int kk = 0; kk < 32; ++kk) mt = fmaxf(mt, s[kk]);
    const float alpha = expf(m - mt);       // m==mt==NEGINF -> expf(0)=1 (wiped later)
    m = mt;
    float ps = 0.f;
#pragma unroll
    for (int kk = 0; kk < 32; ++kk) {
      const float p = expf(s[kk] - mt);
      s[kk] = p;
      ps += p;
    }
    l = l * alpha + ps;
#pragma unroll
    for (int i = 0; i < 32; ++i) o[i] *= alpha;
#pragma unroll
    for (int kk = 0; kk < 32; ++kk) {
      const float p = s[kk];
      const float4* vp = (const float4*)&Vs[kk][sub * 32];
#pragma unroll
      for (int j = 0; j < 8; ++j) {
        const float4 vv = vp[j];
        o[4 * j + 0] = fmaf(p, vv.x, o[4 * j + 0]);
        o[4 * j + 1] = fmaf(p, vv.y, o[4 * j + 1]);
        o[4 * j + 2] = fmaf(p, vv.z, o[4 * j + 2]);
        o[4 * j + 3] = fmaf(p, vv.w, o[4 * j + 3]);
      }
    }
  }

  const float inv = 1.0f / l;
  float* op = out + (size_t)qidx * ODIM + h * D + sub * 32;
#pragma unroll
  for (int i = 0; i < 32; i += 4) {
    *(float4*)(op + i) = make_float4(o[i] * inv, o[i + 1] * inv,
                                     o[i + 2] * inv, o[i + 3] * inv);
  }
}

// ---------------------------------------------------------------------------
// Launch
// ---------------------------------------------------------------------------
extern "C" void kernel_launch(void* const* d_in, const int* in_sizes, int n_in,
                              void* d_out, int out_size, void* d_ws, size_t ws_size,
                              hipStream_t stream) {
  const int*   positions = (const int*)d_in[0];
  const float* hidden    = (const float*)d_in[1];
  const float* w_qkv     = (const float*)d_in[2];
  const float* w_o       = (const float*)d_in[3];
  const float* q_norm_w  = (const float*)d_in[4];
  const float* k_norm_w  = (const float*)d_in[5];
  float* out = (float*)d_out;

  // workspace layout (floats): qkv [T,5120] | attn [T,4096] | cos [T,64] | sin [T,64]
  float* qkv  = (float*)d_ws;
  float* attn = qkv + (size_t)T * QKVW;
  float* cosT = attn + (size_t)T * ODIM;
  float* sinT = cosT + (size_t)T * 64;

  // 1) qkv = hidden @ w_qkv   (M=2048, N=5120, K=2048)
  gemm_f32<<<dim3(QKVW / 128, T / 128), 256, 0, stream>>>(hidden, w_qkv, qkv,
                                                          T, QKVW, HIDDEN);
  // 2) RoPE tables
  rope_tables<<<dim3(T), 64, 0, stream>>>(positions, cosT, sinT);
  // 3) RMSNorm + RoPE on q and k heads (in place)
  norm_rope<<<dim3(T, NH + NKV), 128, 0, stream>>>(qkv, q_norm_w, k_norm_w,
                                                   cosT, sinT);
  // 4) sliding-window attention -> attn [T, 4096]
  attn_swa<<<dim3(NH, T / 64), 256, 0, stream>>>(qkv, attn);
  // 5) out = attn @ w_o       (M=2048, N=2048, K=4096)
  gemm_f32<<<dim3(HIDDEN / 128, T / 128), 256, 0, stream>>>(attn, w_o, out,
                                                            T, HIDDEN, ODIM);
}

// Round 2
// 943.677 us; speedup vs baseline: 2.1706x; 2.1706x over previous
//
#include <hip/hip_runtime.h>
#include <math.h>

// Problem constants
#define T      2048
#define HIDDEN 2048
#define NH     32
#define NKV    4
#define D      128
#define WINDOW 512
#define QKVW   ((NH + 2 * NKV) * D)   // 5120
#define ODIM   (NH * D)               // 4096
#define EPS    1e-6f
#define SCALE  0.08838834764831845f   // D^-0.5
#define NEGINF (-1.0e30f)

typedef _Float16 f16x8 __attribute__((ext_vector_type(8)));
typedef float    f32x4 __attribute__((ext_vector_type(4)));

// ---------------------------------------------------------------------------
// Packed fragment format (both A and B operands of mfma_f32_16x16x32_f16):
//   tiles of 16 (outer) x 32 (k), laid out [kt][outer_tile][chunk=lane][8 f16]
//   chunk c = q*16 + o  (q = lane>>4, o = lane&15), chunk holds 8 k-consecutive
//   values at outer index o, k = kt*32 + q*8 + j.
// A-operand (verified m89/m120): lane holds A[m=lane&15][k=(lane>>4)*8+j]
// B-operand (mirror):           lane holds B[k=(lane>>4)*8+j][n=lane&15]
// So a wave's frag read is LDS_base + lane*16 (contiguous 1KB/tile), and
// global_load_lds (dest = uniform base + lane*16) streams tiles directly.
// ---------------------------------------------------------------------------

// pack A: [M][K] fp32 row-major -> packed f16 chunks (k consecutive in source)
__global__ __launch_bounds__(256)
void pack_a(const float* __restrict__ A, _Float16* __restrict__ out,
            int M, int K) {
  const int cid = blockIdx.x * 256 + threadIdx.x;      // one 16B chunk/thread
  const int c = cid & 63;
  const int tile = cid >> 6;                           // kt*(M/16) + mtg
  const int mtg = tile % (M >> 4);
  const int kt = tile / (M >> 4);
  const int m = c & 15, q = c >> 4;
  const float* src = A + (size_t)(mtg * 16 + m) * K + kt * 32 + q * 8;
  const float4 a = *(const float4*)src;
  const float4 b = *(const float4*)(src + 4);
  f16x8 h;
  h[0] = (_Float16)a.x; h[1] = (_Float16)a.y; h[2] = (_Float16)a.z; h[3] = (_Float16)a.w;
  h[4] = (_Float16)b.x; h[5] = (_Float16)b.y; h[6] = (_Float16)b.z; h[7] = (_Float16)b.w;
  *(f16x8*)(out + (size_t)cid * 8) = h;
}

// pack B: [K][N] fp32 row-major -> packed f16 chunks (k strided in source)
__global__ __launch_bounds__(256)
void pack_b(const float* __restrict__ B, _Float16* __restrict__ out,
            int K, int N) {
  const int cid = blockIdx.x * 256 + threadIdx.x;
  const int c = cid & 63;
  const int tile = cid >> 6;                           // kt*(N/16) + ntg
  const int ntg = tile % (N >> 4);
  const int kt = tile / (N >> 4);
  const int n = c & 15, q = c >> 4;
  const float* src = B + (size_t)(kt * 32 + q * 8) * N + ntg * 16 + n;
  f16x8 h;
#pragma unroll
  for (int j = 0; j < 8; ++j) h[j] = (_Float16)src[(size_t)j * N];
  *(f16x8*)(out + (size_t)cid * 8) = h;
}

__device__ __forceinline__ void gl2lds16(const void* g, void* l) {
  __builtin_amdgcn_global_load_lds((const __attribute__((address_space(1))) void*)g,
                                   (__attribute__((address_space(3))) void*)l,
                                   16, 0, 0);
}

// ---------------------------------------------------------------------------
// fp16 MFMA GEMM: C[M,N](f32) = Apk * Bpk, BM=128, BK=32, 256 thr = 4 waves
// (2x2 over the tile). Per K-step per wave: (BN==128) 16 MFMA + 8 ds_read_b128
// + 4 global_load_lds_dwordx4 — the m97 histogram.
// ---------------------------------------------------------------------------
template<int BN>
__global__ __launch_bounds__(256)
void gemm_f16(const _Float16* __restrict__ Apk, const _Float16* __restrict__ Bpk,
              float* __restrict__ C, int M, int N, int K) {
  constexpr int BM = 128;
  constexpr int AT = BM / 16;          // 8 A tiles
  constexpr int BT = BN / 16;          // 8 or 4 B tiles
  constexpr int RT = 4;                // 16-row tiles per wave
  constexpr int CT = BN / 32;          // 16-col tiles per wave
  __shared__ _Float16 As[AT * 512];
  __shared__ _Float16 Bs[BT * 512];

  const int tid = threadIdx.x;
  const int lane = tid & 63;
  const int wv = tid >> 6;
  const int wr = wv & 1, wc = wv >> 1;
  const int mtg0 = blockIdx.y * AT;
  const int ntg0 = blockIdx.x * BT;
  const int KT = K >> 5;

  f32x4 acc[RT][CT];
#pragma unroll
  for (int i = 0; i < RT; ++i)
#pragma unroll
    for (int j = 0; j < CT; ++j) acc[i][j] = (f32x4)0.f;

  const char* Ag = (const char*)Apk + (size_t)mtg0 * 1024 + lane * 16;
  const char* Bg = (const char*)Bpk + (size_t)ntg0 * 1024 + lane * 16;
  const size_t Astep = (size_t)(M >> 4) * 1024;   // bytes per kt
  const size_t Bstep = (size_t)(N >> 4) * 1024;

  for (int kt = 0; kt < KT; ++kt) {
    const char* ab = Ag + kt * Astep;
    const char* bb = Bg + kt * Bstep;
#pragma unroll
    for (int t = wv; t < AT + BT; t += 4) {
      if (t < AT) gl2lds16(ab + t * 1024, (char*)As + t * 1024);
      else        gl2lds16(bb + (t - AT) * 1024, (char*)Bs + (t - AT) * 1024);
    }
    __syncthreads();   // compiler drains vmcnt(0) before s_barrier

    f16x8 af[RT], bf[CT];
#pragma unroll
    for (int i = 0; i < RT; ++i)
      af[i] = *(const f16x8*)((const char*)As + (wr * RT + i) * 1024 + lane * 16);
#pragma unroll
    for (int j = 0; j < CT; ++j)
      bf[j] = *(const f16x8*)((const char*)Bs + (wc * CT + j) * 1024 + lane * 16);
#pragma unroll
    for (int i = 0; i < RT; ++i)
#pragma unroll
      for (int j = 0; j < CT; ++j)
        acc[i][j] = __builtin_amdgcn_mfma_f32_16x16x32_f16(af[i], bf[j], acc[i][j], 0, 0, 0);
    __syncthreads();
  }

  // epilogue: C/D layout col=lane&15, row=(lane>>4)*4+reg (m89, dtype-indep)
  const int row0 = blockIdx.y * BM + wr * 64 + ((lane >> 4) << 2);
  const int col0 = blockIdx.x * BN + wc * (CT * 16) + (lane & 15);
#pragma unroll
  for (int i = 0; i < RT; ++i)
#pragma unroll
    for (int j = 0; j < CT; ++j) {
#pragma unroll
      for (int r = 0; r < 4; ++r)
        C[(size_t)(row0 + i * 16 + r) * N + col0 + j * 16] = acc[i][j][r];
    }
}

// ---------------------------------------------------------------------------
// RoPE tables. fp32 pipeline to match the reference's fp32 computation
// (inv_freq rounded from double; ang = fp32(pos * inv_freq); fp32 sin/cos).
// ---------------------------------------------------------------------------
__global__ __launch_bounds__(64)
void rope_tables(const int* __restrict__ positions,
                 float* __restrict__ cosT, float* __restrict__ sinT) {
  const int j = threadIdx.x;               // freq index 0..63
  const int p0 = blockIdx.x * 64;
  const float invf = (float)pow(1.0e6, -(double)j / 64.0);
#pragma unroll 4
  for (int i = 0; i < 64; ++i) {
    const int t = p0 + i;
    const float ang = (float)positions[t] * invf;
    cosT[t * 64 + j] = cosf(ang);
    sinT[t * 64 + j] = sinf(ang);
  }
}

// ---------------------------------------------------------------------------
// fused RMSNorm + RoPE, in place on qkv (q and k heads).
// ---------------------------------------------------------------------------
__global__ __launch_bounds__(128)
void norm_rope(float* __restrict__ qkv,
               const float* __restrict__ qw, const float* __restrict__ kw,
               const float* __restrict__ cosT, const float* __restrict__ sinT) {
  const int t = blockIdx.x;
  const int hh = blockIdx.y;
  const int d = threadIdx.x;               // 0..127

  float* x;
  const float* w;
  if (hh < NH) { x = qkv + (size_t)t * QKVW + hh * D;                 w = qw; }
  else         { x = qkv + (size_t)t * QKVW + NH * D + (hh - NH) * D; w = kw; }

  const float v = x[d];
  float ss = v * v;
#pragma unroll
  for (int off = 32; off >= 1; off >>= 1) ss += __shfl_xor(ss, off);

  __shared__ float sred[2];
  if ((d & 63) == 0) sred[d >> 6] = ss;
  __syncthreads();
  const float total = sred[0] + sred[1];
  const float r = 1.0f / sqrtf(total * (1.0f / D) + EPS);
  const float nv = v * r * w[d];

  __shared__ float buf[D];
  buf[d] = nv;
  __syncthreads();

  const int j = d & 63;
  const float c = cosT[t * 64 + j];
  const float s = sinT[t * 64 + j];
  const float x1 = buf[j];
  const float x2 = buf[j + 64];
  x[d] = (d < 64) ? (x1 * c - x2 * s) : (x2 * c + x1 * s);
}

// ---------------------------------------------------------------------------
// sliding-window causal attention, flash-style online softmax (fp32).
// ---------------------------------------------------------------------------
__global__ __launch_bounds__(256)
void attn_swa(const float* __restrict__ qkv, float* __restrict__ out) {
  const int h = blockIdx.x;
  const int q0 = blockIdx.y * 64;
  const int kvh = h >> 3;
  const int tid = threadIdx.x;
  const int g = tid >> 2;
  const int sub = tid & 3;
  const int qidx = q0 + g;

  __shared__ float Ks[32][D];
  __shared__ float Vs[32][D];

  float q[32], o[32];
  const float* qp = qkv + (size_t)qidx * QKVW + h * D + sub * 32;
#pragma unroll
  for (int i = 0; i < 32; i += 4) *(float4*)&q[i] = *(const float4*)(qp + i);
#pragma unroll
  for (int i = 0; i < 32; ++i) o[i] = 0.f;

  float m = NEGINF, l = 0.f;

  int kstart = q0 - (WINDOW - 1);
  if (kstart < 0) kstart = 0;
  kstart &= ~31;
  const int kend = q0 + 64;

  for (int kt = kstart; kt < kend; kt += 32) {
    __syncthreads();
#pragma unroll
    for (int i = tid * 4; i < 32 * D; i += 256 * 4) {
      const int kk = i >> 7;
      const int dd = i & 127;
      const float* base = qkv + (size_t)(kt + kk) * QKVW + NH * D + kvh * D + dd;
      *(float4*)&Ks[kk][dd] = *(const float4*)base;
      *(float4*)&Vs[kk][dd] = *(const float4*)(base + NKV * D);
    }
    __syncthreads();

    float s[32];
#pragma unroll
    for (int kk = 0; kk < 32; ++kk) {
      const float4* kp = (const float4*)&Ks[kk][sub * 32];
      float p = 0.f;
#pragma unroll
      for (int j = 0; j < 8; ++j) {
        const float4 kv = kp[j];
        p = fmaf(q[4 * j + 0], kv.x, p);
        p = fmaf(q[4 * j + 1], kv.y, p);
        p = fmaf(q[4 * j + 2], kv.z, p);
        p = fmaf(q[4 * j + 3], kv.w, p);
      }
      p += __shfl_xor(p, 1);
      p += __shfl_xor(p, 2);
      const int kidx = kt + kk;
      const bool valid = (kidx <= qidx) && (qidx - kidx < WINDOW);
      s[kk] = valid ? p * SCALE : NEGINF;
    }

    float mt = m;
#pragma unroll
    for (int kk = 0; kk < 32; ++kk) mt = fmaxf(mt, s[kk]);
    const float alpha = expf(m - mt);
    m = mt;
    float ps = 0.f;
#pragma unroll
    for (int kk = 0; kk < 32; ++kk) {
      const float p = expf(s[kk] - mt);
      s[kk] = p;
      ps += p;
    }
    l = l * alpha + ps;
#pragma unroll
    for (int i = 0; i < 32; ++i) o[i] *= alpha;
#pragma unroll
    for (int kk = 0; kk < 32; ++kk) {
      const float p = s[kk];
      const float4* vp = (const float4*)&Vs[kk][sub * 32];
#pragma unroll
      for (int j = 0; j < 8; ++j) {
        const float4 vv = vp[j];
        o[4 * j + 0] = fmaf(p, vv.x, o[4 * j + 0]);
        o[4 * j + 1] = fmaf(p, vv.y, o[4 * j + 1]);
        o[4 * j + 2] = fmaf(p, vv.z, o[4 * j + 2]);
        o[4 * j + 3] = fmaf(p, vv.w, o[4 * j + 3]);
      }
    }
  }

  const float inv = 1.0f / l;
  float* op = out + (size_t)qidx * ODIM + h * D + sub * 32;
#pragma unroll
  for (int i = 0; i < 32; i += 4) {
    *(float4*)(op + i) = make_float4(o[i] * inv, o[i + 1] * inv,
                                     o[i + 2] * inv, o[i + 3] * inv);
  }
}

// ---------------------------------------------------------------------------
// Launch
// ---------------------------------------------------------------------------
extern "C" void kernel_launch(void* const* d_in, const int* in_sizes, int n_in,
                              void* d_out, int out_size, void* d_ws, size_t ws_size,
                              hipStream_t stream) {
  const int*   positions = (const int*)d_in[0];
  const float* hidden    = (const float*)d_in[1];
  const float* w_qkv     = (const float*)d_in[2];
  const float* w_o       = (const float*)d_in[3];
  const float* q_norm_w  = (const float*)d_in[4];
  const float* k_norm_w  = (const float*)d_in[5];
  float* out = (float*)d_out;

  // workspace layout
  char* ws = (char*)d_ws;
  float* qkv  = (float*)ws;                                  ws += (size_t)T * QKVW * 4;   // 41.9 MB
  float* attn = (float*)ws;                                  ws += (size_t)T * ODIM * 4;   // 33.6 MB
  float* cosT = (float*)ws;                                  ws += (size_t)T * 64 * 4;
  float* sinT = (float*)ws;                                  ws += (size_t)T * 64 * 4;
  _Float16* Ah1 = (_Float16*)ws;                             ws += (size_t)T * HIDDEN * 2; // 8.4 MB
  _Float16* Bp1 = (_Float16*)ws;                             ws += (size_t)HIDDEN * QKVW * 2; // 21 MB
  _Float16* Ap2 = (_Float16*)ws;                             ws += (size_t)T * ODIM * 2;   // 16.8 MB
  _Float16* Bp2 = (_Float16*)ws;                             ws += (size_t)ODIM * HIDDEN * 2; // 16.8 MB

  // pack inputs to MFMA-fragment order (f16)
  pack_a<<<dim3((size_t)T * HIDDEN / 8 / 256), 256, 0, stream>>>(hidden, Ah1, T, HIDDEN);
  pack_b<<<dim3((size_t)HIDDEN * QKVW / 8 / 256), 256, 0, stream>>>(w_qkv, Bp1, HIDDEN, QKVW);
  pack_b<<<dim3((size_t)ODIM * HIDDEN / 8 / 256), 256, 0, stream>>>(w_o, Bp2, ODIM, HIDDEN);

  // 1) qkv = hidden @ w_qkv   (M=2048, N=5120, K=2048)
  gemm_f16<128><<<dim3(QKVW / 128, T / 128), 256, 0, stream>>>(Ah1, Bp1, qkv,
                                                               T, QKVW, HIDDEN);
  // 2) RoPE tables
  rope_tables<<<dim3(T / 64), 64, 0, stream>>>(positions, cosT, sinT);
  // 3) RMSNorm + RoPE on q and k heads (in place, fp32)
  norm_rope<<<dim3(T, NH + NKV), 128, 0, stream>>>(qkv, q_norm_w, k_norm_w,
                                                   cosT, sinT);
  // 4) sliding-window attention -> attn [T, 4096] (fp32)
  attn_swa<<<dim3(NH, T / 64), 256, 0, stream>>>(qkv, attn);
  // 5) pack attn, then out = attn @ w_o (M=2048, N=2048, K=4096)
  pack_a<<<dim3((size_t)T * ODIM / 8 / 256), 256, 0, stream>>>(attn, Ap2, T, ODIM);
  gemm_f16<64><<<dim3(HIDDEN / 64, T / 128), 256, 0, stream>>>(Ap2, Bp2, out,
                                                               T, HIDDEN, ODIM);
}

// Round 3
// 386.983 us; speedup vs baseline: 5.2930x; 2.4385x over previous
//
#include <hip/hip_runtime.h>
#include <math.h>

// Problem constants
#define T      2048
#define HIDDEN 2048
#define NH     32
#define NKV    4
#define D      128
#define WINDOW 512
#define QKVW   ((NH + 2 * NKV) * D)   // 5120
#define ODIM   (NH * D)               // 4096
#define EPS    1e-6f
#define SCALE  0.08838834764831845f   // D^-0.5
#define NEGINF (-1.0e30f)
#define PSTR   72                     // P-slab LDS row stride (fp16), padded

typedef _Float16 f16x8 __attribute__((ext_vector_type(8)));
typedef float    f32x4 __attribute__((ext_vector_type(4)));

// ---------------------------------------------------------------------------
// Packed fragment format (validated in R2 GEMM):
// chunk c = q*16 + o (q=c>>4, o=c&15), chunk = 8 k-consecutive f16 at outer o.
// A-operand: lane holds A[m=lane&15][k=(lane>>4)*8+j]
// B-operand: lane holds B[k=(lane>>4)*8+j][n=lane&15]
// ---------------------------------------------------------------------------

__global__ __launch_bounds__(256)
void pack_a(const float* __restrict__ A, _Float16* __restrict__ out,
            int M, int K) {
  const int cid = blockIdx.x * 256 + threadIdx.x;
  const int c = cid & 63;
  const int tile = cid >> 6;
  const int mtg = tile % (M >> 4);
  const int kt = tile / (M >> 4);
  const int m = c & 15, q = c >> 4;
  const float* src = A + (size_t)(mtg * 16 + m) * K + kt * 32 + q * 8;
  const float4 a = *(const float4*)src;
  const float4 b = *(const float4*)(src + 4);
  f16x8 h;
  h[0] = (_Float16)a.x; h[1] = (_Float16)a.y; h[2] = (_Float16)a.z; h[3] = (_Float16)a.w;
  h[4] = (_Float16)b.x; h[5] = (_Float16)b.y; h[6] = (_Float16)b.z; h[7] = (_Float16)b.w;
  *(f16x8*)(out + (size_t)cid * 8) = h;
}

__global__ __launch_bounds__(256)
void pack_b(const float* __restrict__ B, _Float16* __restrict__ out,
            int K, int N) {
  const int cid = blockIdx.x * 256 + threadIdx.x;
  const int c = cid & 63;
  const int tile = cid >> 6;
  const int ntg = tile % (N >> 4);
  const int kt = tile / (N >> 4);
  const int n = c & 15, q = c >> 4;
  const float* src = B + (size_t)(kt * 32 + q * 8) * N + ntg * 16 + n;
  f16x8 h;
#pragma unroll
  for (int j = 0; j < 8; ++j) h[j] = (_Float16)src[(size_t)j * N];
  *(f16x8*)(out + (size_t)cid * 8) = h;
}

__device__ __forceinline__ void gl2lds16(const void* g, void* l) {
  __builtin_amdgcn_global_load_lds((const __attribute__((address_space(1))) void*)g,
                                   (__attribute__((address_space(3))) void*)l,
                                   16, 0, 0);
}

// ---------------------------------------------------------------------------
// fp16 MFMA GEMM (validated R2): BM=128, BK=32, 256 thr = 4 waves 2x2.
// ---------------------------------------------------------------------------
template<int BN>
__global__ __launch_bounds__(256)
void gemm_f16(const _Float16* __restrict__ Apk, const _Float16* __restrict__ Bpk,
              float* __restrict__ C, int M, int N, int K) {
  constexpr int BM = 128;
  constexpr int AT = BM / 16;
  constexpr int BT = BN / 16;
  constexpr int RT = 4;
  constexpr int CT = BN / 32;
  __shared__ _Float16 As[AT * 512];
  __shared__ _Float16 Bs[BT * 512];

  const int tid = threadIdx.x;
  const int lane = tid & 63;
  const int wv = tid >> 6;
  const int wr = wv & 1, wc = wv >> 1;
  const int mtg0 = blockIdx.y * AT;
  const int ntg0 = blockIdx.x * BT;
  const int KT = K >> 5;

  f32x4 acc[RT][CT];
#pragma unroll
  for (int i = 0; i < RT; ++i)
#pragma unroll
    for (int j = 0; j < CT; ++j) acc[i][j] = (f32x4)0.f;

  const char* Ag = (const char*)Apk + (size_t)mtg0 * 1024 + lane * 16;
  const char* Bg = (const char*)Bpk + (size_t)ntg0 * 1024 + lane * 16;
  const size_t Astep = (size_t)(M >> 4) * 1024;
  const size_t Bstep = (size_t)(N >> 4) * 1024;

  for (int kt = 0; kt < KT; ++kt) {
    const char* ab = Ag + kt * Astep;
    const char* bb = Bg + kt * Bstep;
#pragma unroll
    for (int t = wv; t < AT + BT; t += 4) {
      if (t < AT) gl2lds16(ab + t * 1024, (char*)As + t * 1024);
      else        gl2lds16(bb + (t - AT) * 1024, (char*)Bs + (t - AT) * 1024);
    }
    __syncthreads();

    f16x8 af[RT], bf[CT];
#pragma unroll
    for (int i = 0; i < RT; ++i)
      af[i] = *(const f16x8*)((const char*)As + (wr * RT + i) * 1024 + lane * 16);
#pragma unroll
    for (int j = 0; j < CT; ++j)
      bf[j] = *(const f16x8*)((const char*)Bs + (wc * CT + j) * 1024 + lane * 16);
#pragma unroll
    for (int i = 0; i < RT; ++i)
#pragma unroll
      for (int j = 0; j < CT; ++j)
        acc[i][j] = __builtin_amdgcn_mfma_f32_16x16x32_f16(af[i], bf[j], acc[i][j], 0, 0, 0);
    __syncthreads();
  }

  const int row0 = blockIdx.y * BM + wr * 64 + ((lane >> 4) << 2);
  const int col0 = blockIdx.x * BN + wc * (CT * 16) + (lane & 15);
#pragma unroll
  for (int i = 0; i < RT; ++i)
#pragma unroll
    for (int j = 0; j < CT; ++j) {
#pragma unroll
      for (int r = 0; r < 4; ++r)
        C[(size_t)(row0 + i * 16 + r) * N + col0 + j * 16] = acc[i][j][r];
    }
}

// ---------------------------------------------------------------------------
// RoPE tables (fp32 pipeline, matches reference fp32 math)
// ---------------------------------------------------------------------------
__global__ __launch_bounds__(64)
void rope_tables(const int* __restrict__ positions,
                 float* __restrict__ cosT, float* __restrict__ sinT) {
  const int j = threadIdx.x;
  const int p0 = blockIdx.x * 64;
  const float invf = (float)pow(1.0e6, -(double)j / 64.0);
#pragma unroll 4
  for (int i = 0; i < 64; ++i) {
    const int t = p0 + i;
    const float ang = (float)positions[t] * invf;
    cosT[t * 64 + j] = cosf(ang);
    sinT[t * 64 + j] = sinf(ang);
  }
}

// ---------------------------------------------------------------------------
// fused RMSNorm + RoPE, in place on qkv q/k heads (fp32)
// ---------------------------------------------------------------------------
__global__ __launch_bounds__(128)
void norm_rope(float* __restrict__ qkv,
               const float* __restrict__ qw, const float* __restrict__ kw,
               const float* __restrict__ cosT, const float* __restrict__ sinT) {
  const int t = blockIdx.x;
  const int hh = blockIdx.y;
  const int d = threadIdx.x;

  float* x;
  const float* w;
  if (hh < NH) { x = qkv + (size_t)t * QKVW + hh * D;                 w = qw; }
  else         { x = qkv + (size_t)t * QKVW + NH * D + (hh - NH) * D; w = kw; }

  const float v = x[d];
  float ss = v * v;
#pragma unroll
  for (int off = 32; off >= 1; off >>= 1) ss += __shfl_xor(ss, off);

  __shared__ float sred[2];
  if ((d & 63) == 0) sred[d >> 6] = ss;
  __syncthreads();
  const float total = sred[0] + sred[1];
  const float r = 1.0f / sqrtf(total * (1.0f / D) + EPS);
  const float nv = v * r * w[d];

  __shared__ float buf[D];
  buf[d] = nv;
  __syncthreads();

  const int j = d & 63;
  const float c = cosT[t * 64 + j];
  const float s = sinT[t * 64 + j];
  const float x1 = buf[j];
  const float x2 = buf[j + 64];
  x[d] = (d < 64) ? (x1 * c - x2 * s) : (x2 * c + x1 * s);
}

// ---------------------------------------------------------------------------
// Attention pre-pack kernels: fp32 qkv -> fragment-ready fp16 global buffers.
// Qpk: [h32][qt128][ds4][c64][8]  A-operand per 16-query tile
// Kpk: [kvh4][ktile128][ds4][c64][8]  B-operand of Q*K^T (== A-format of K)
// Vpk: [kvh4][kt64 32][ks2][dt8][c64][8]  B-operand of P*V
// ---------------------------------------------------------------------------
__global__ __launch_bounds__(256)
void pack_q(const float* __restrict__ qkv, _Float16* __restrict__ out) {
  const int cid = blockIdx.x * 256 + threadIdx.x;   // < 2^20
  const int c = cid & 63;
  const int ds = (cid >> 6) & 3;
  const int qt = (cid >> 8) & 127;
  const int h = cid >> 15;
  const int query = qt * 16 + (c & 15);
  const int d = ds * 32 + (c >> 4) * 8;
  const float* src = qkv + (size_t)query * QKVW + h * D + d;
  const float4 a = *(const float4*)src;
  const float4 b = *(const float4*)(src + 4);
  f16x8 h8;
  h8[0] = (_Float16)a.x; h8[1] = (_Float16)a.y; h8[2] = (_Float16)a.z; h8[3] = (_Float16)a.w;
  h8[4] = (_Float16)b.x; h8[5] = (_Float16)b.y; h8[6] = (_Float16)b.z; h8[7] = (_Float16)b.w;
  *(f16x8*)(out + (size_t)cid * 8) = h8;
}

__global__ __launch_bounds__(256)
void pack_k(const float* __restrict__ qkv, _Float16* __restrict__ out) {
  const int cid = blockIdx.x * 256 + threadIdx.x;   // < 2^17
  const int c = cid & 63;
  const int ds = (cid >> 6) & 3;
  const int ktile = (cid >> 8) & 127;
  const int kvh = cid >> 15;
  const int key = ktile * 16 + (c & 15);
  const int d = ds * 32 + (c >> 4) * 8;
  const float* src = qkv + (size_t)key * QKVW + NH * D + kvh * D + d;
  const float4 a = *(const float4*)src;
  const float4 b = *(const float4*)(src + 4);
  f16x8 h8;
  h8[0] = (_Float16)a.x; h8[1] = (_Float16)a.y; h8[2] = (_Float16)a.z; h8[3] = (_Float16)a.w;
  h8[4] = (_Float16)b.x; h8[5] = (_Float16)b.y; h8[6] = (_Float16)b.z; h8[7] = (_Float16)b.w;
  *(f16x8*)(out + (size_t)cid * 8) = h8;
}

__global__ __launch_bounds__(256)
void pack_v(const float* __restrict__ qkv, _Float16* __restrict__ out) {
  const int cid = blockIdx.x * 256 + threadIdx.x;   // < 2^17
  const int c = cid & 63;
  const int dt = (cid >> 6) & 7;
  const int ks = (cid >> 9) & 1;
  const int kt64 = (cid >> 10) & 31;
  const int kvh = cid >> 15;
  const int key = kt64 * 64 + ks * 32 + (c >> 4) * 8;
  const int d = dt * 16 + (c & 15);
  const float* src = qkv + (size_t)key * QKVW + (NH + NKV) * D + kvh * D + d;
  f16x8 h8;
#pragma unroll
  for (int j = 0; j < 8; ++j) h8[j] = (_Float16)src[(size_t)j * QKVW];
  *(f16x8*)(out + (size_t)cid * 8) = h8;
}

// ---------------------------------------------------------------------------
// MFMA flash attention, sliding window. grid(NH, T/64), 256 thr = 4 waves.
// Wave owns 16 queries x full D. 64-key K/V tiles staged to LDS.
// Masked rows use the -1e30 wipe trick (alpha=0 on first real key).
// ---------------------------------------------------------------------------
__global__ __launch_bounds__(256)
void attn_mfma(const _Float16* __restrict__ Qpk, const _Float16* __restrict__ Kpk,
               const _Float16* __restrict__ Vpk, float* __restrict__ out) {
  const int h = blockIdx.x;
  const int q0 = blockIdx.y * 64;
  const int kvh = h >> 3;
  const int tid = threadIdx.x;
  const int lane = tid & 63;
  const int wv = tid >> 6;
  const int l15 = lane & 15;
  const int l4 = lane >> 4;

  __shared__ _Float16 Ks[16 * 512];          // [keytile4][ds4][lane64][8]
  __shared__ _Float16 Vs[16 * 512];          // [ks2][dt8][lane64][8]
  __shared__ _Float16 Ps[4 * 16 * PSTR];     // per-wave 16x64 P slab

  // Q A-frags, one per 32-d step
  f16x8 qf[4];
  {
    const _Float16* qb = Qpk + (size_t)(h * 128 + (q0 >> 4) + wv) * 2048 + lane * 8;
#pragma unroll
    for (int ds = 0; ds < 4; ++ds) qf[ds] = *(const f16x8*)(qb + ds * 512);
  }

  f32x4 O[8];
#pragma unroll
  for (int dt = 0; dt < 8; ++dt) O[dt] = (f32x4)0.f;
  float mrow[4], lrow[4];
#pragma unroll
  for (int r = 0; r < 4; ++r) { mrow[r] = NEGINF; lrow[r] = 0.f; }

  int kstart = q0 - (WINDOW - 1);
  if (kstart < 0) kstart = 0;
  kstart &= ~63;

  _Float16* Pw = Ps + wv * 16 * PSTR;

  for (int kt = kstart; kt < q0 + 64; kt += 64) {
    __syncthreads();
    const _Float16* Kg = Kpk + ((size_t)kvh * 128 + (kt >> 4)) * 2048 + lane * 8;
    const _Float16* Vg = Vpk + ((size_t)kvh * 32 + (kt >> 6)) * 8192 + lane * 8;
#pragma unroll
    for (int t = wv; t < 16; t += 4) {
      gl2lds16(Kg + t * 512, (char*)Ks + t * 1024);
      gl2lds16(Vg + t * 512, (char*)Vs + t * 1024);
    }
    __syncthreads();

    // S = Q K^T : 16 queries x 64 keys per wave
    f32x4 acc[4];
#pragma unroll
    for (int nt = 0; nt < 4; ++nt) acc[nt] = (f32x4)0.f;
#pragma unroll
    for (int ds = 0; ds < 4; ++ds) {
#pragma unroll
      for (int nt = 0; nt < 4; ++nt) {
        const f16x8 kf = *(const f16x8*)(Ks + (nt * 4 + ds) * 512 + lane * 8);
        acc[nt] = __builtin_amdgcn_mfma_f32_16x16x32_f16(qf[ds], kf, acc[nt], 0, 0, 0);
      }
    }

    // mask + scale (C-layout: row=query=l4*4+r, col=key=nt*16+l15)
    const int qbase = q0 + wv * 16 + l4 * 4;
    const int kbase = kt + l15;
#pragma unroll
    for (int nt = 0; nt < 4; ++nt) {
#pragma unroll
      for (int r = 0; r < 4; ++r) {
        const int delta = (qbase + r) - (kbase + nt * 16);
        acc[nt][r] = ((unsigned)delta < WINDOW) ? acc[nt][r] * SCALE : NEGINF;
      }
    }

    // online softmax per query row
    float p[4][4], alpha[4];
#pragma unroll
    for (int r = 0; r < 4; ++r) {
      float mx = fmaxf(fmaxf(acc[0][r], acc[1][r]), fmaxf(acc[2][r], acc[3][r]));
      mx = fmaxf(mx, __shfl_xor(mx, 1));
      mx = fmaxf(mx, __shfl_xor(mx, 2));
      mx = fmaxf(mx, __shfl_xor(mx, 4));
      mx = fmaxf(mx, __shfl_xor(mx, 8));
      const float mt = fmaxf(mrow[r], mx);
      alpha[r] = expf(mrow[r] - mt);
      mrow[r] = mt;
      float s = 0.f;
#pragma unroll
      for (int nt = 0; nt < 4; ++nt) {
        const float pv = expf(acc[nt][r] - mt);
        p[nt][r] = pv;
        s += pv;
      }
      s += __shfl_xor(s, 1);
      s += __shfl_xor(s, 2);
      s += __shfl_xor(s, 4);
      s += __shfl_xor(s, 8);
      lrow[r] = lrow[r] * alpha[r] + s;
    }
#pragma unroll
    for (int dt = 0; dt < 8; ++dt)
#pragma unroll
      for (int r = 0; r < 4; ++r) O[dt][r] *= alpha[r];

    // P -> LDS (row-major 16x64, stride PSTR); wave-private, no barrier needed
#pragma unroll
    for (int nt = 0; nt < 4; ++nt)
#pragma unroll
      for (int r = 0; r < 4; ++r)
        Pw[(l4 * 4 + r) * PSTR + nt * 16 + l15] = (_Float16)p[nt][r];

    // O += P V
#pragma unroll
    for (int ks = 0; ks < 2; ++ks) {
      const f16x8 pf = *(const f16x8*)(Pw + l15 * PSTR + ks * 32 + l4 * 8);
#pragma unroll
      for (int dt = 0; dt < 8; ++dt) {
        const f16x8 vf = *(const f16x8*)(Vs + (ks * 8 + dt) * 512 + lane * 8);
        O[dt] = __builtin_amdgcn_mfma_f32_16x16x32_f16(pf, vf, O[dt], 0, 0, 0);
      }
    }
  }

  float inv[4];
#pragma unroll
  for (int r = 0; r < 4; ++r) inv[r] = 1.0f / lrow[r];
  const int qq = q0 + wv * 16 + l4 * 4;
#pragma unroll
  for (int dt = 0; dt < 8; ++dt)
#pragma unroll
    for (int r = 0; r < 4; ++r)
      out[(size_t)(qq + r) * ODIM + h * D + dt * 16 + l15] = O[dt][r] * inv[r];
}

// ---------------------------------------------------------------------------
// Launch
// ---------------------------------------------------------------------------
extern "C" void kernel_launch(void* const* d_in, const int* in_sizes, int n_in,
                              void* d_out, int out_size, void* d_ws, size_t ws_size,
                              hipStream_t stream) {
  const int*   positions = (const int*)d_in[0];
  const float* hidden    = (const float*)d_in[1];
  const float* w_qkv     = (const float*)d_in[2];
  const float* w_o       = (const float*)d_in[3];
  const float* q_norm_w  = (const float*)d_in[4];
  const float* k_norm_w  = (const float*)d_in[5];
  float* out = (float*)d_out;

  // workspace layout (139.5 MB total, same footprint as R2 via aliasing)
  char* ws = (char*)d_ws;
  float* qkv  = (float*)ws;  ws += (size_t)T * QKVW * 4;          // 41.9 MB
  float* attn = (float*)ws;  ws += (size_t)T * ODIM * 4;          // 33.6 MB
  float* cosT = (float*)ws;  ws += (size_t)T * 64 * 4;
  float* sinT = (float*)ws;  ws += (size_t)T * 64 * 4;
  _Float16* Bp1 = (_Float16*)ws; ws += (size_t)HIDDEN * QKVW * 2; // 21.0 MB
  _Float16* Bp2 = (_Float16*)ws; ws += (size_t)ODIM * HIDDEN * 2; // 16.8 MB
  // region X: Ah1 (dead after gemm1) aliased with Kpk+Vpk (written after)
  _Float16* Ah1 = (_Float16*)ws;
  _Float16* Kpk = (_Float16*)ws;
  _Float16* Vpk = Kpk + (size_t)T * NKV * D;
  ws += (size_t)T * HIDDEN * 2;                                   // 8.4 MB
  // region Y: Qpk (dead after attn) aliased with Ap2 (written after)
  _Float16* Qpk = (_Float16*)ws;
  _Float16* Ap2 = (_Float16*)ws;
  ws += (size_t)T * ODIM * 2;                                     // 16.8 MB

  // pack GEMM operands
  pack_a<<<dim3((size_t)T * HIDDEN / 8 / 256), 256, 0, stream>>>(hidden, Ah1, T, HIDDEN);
  pack_b<<<dim3((size_t)HIDDEN * QKVW / 8 / 256), 256, 0, stream>>>(w_qkv, Bp1, HIDDEN, QKVW);
  pack_b<<<dim3((size_t)ODIM * HIDDEN / 8 / 256), 256, 0, stream>>>(w_o, Bp2, ODIM, HIDDEN);

  // 1) qkv = hidden @ w_qkv
  gemm_f16<128><<<dim3(QKVW / 128, T / 128), 256, 0, stream>>>(Ah1, Bp1, qkv,
                                                               T, QKVW, HIDDEN);
  // 2) RoPE tables + RMSNorm/RoPE
  rope_tables<<<dim3(T / 64), 64, 0, stream>>>(positions, cosT, sinT);
  norm_rope<<<dim3(T, NH + NKV), 128, 0, stream>>>(qkv, q_norm_w, k_norm_w,
                                                   cosT, sinT);
  // 3) pack Q/K/V to fragment order (fp16); Kpk/Vpk overwrite Ah1 (dead)
  pack_q<<<dim3(1048576 / 256), 256, 0, stream>>>(qkv, Qpk);
  pack_k<<<dim3(131072 / 256), 256, 0, stream>>>(qkv, Kpk);
  pack_v<<<dim3(131072 / 256), 256, 0, stream>>>(qkv, Vpk);
  // 4) MFMA flash attention
  attn_mfma<<<dim3(NH, T / 64), 256, 0, stream>>>(Qpk, Kpk, Vpk, attn);
  // 5) pack attn (overwrites Qpk, dead) and output projection
  pack_a<<<dim3((size_t)T * ODIM / 8 / 256), 256, 0, stream>>>(attn, Ap2, T, ODIM);
  gemm_f16<64><<<dim3(HIDDEN / 64, T / 128), 256, 0, stream>>>(Ap2, Bp2, out,
                                                               T, HIDDEN, ODIM);
}

// Round 4
// 327.947 us; speedup vs baseline: 6.2458x; 1.1800x over previous
//
#include <hip/hip_runtime.h>
#include <math.h>

// Problem constants
#define T      2048
#define HIDDEN 2048
#define NH     32
#define NKV    4
#define D      128
#define WINDOW 512
#define QKVW   ((NH + 2 * NKV) * D)   // 5120
#define ODIM   (NH * D)               // 4096
#define EPS    1e-6f
#define SCALE  0.08838834764831845f   // D^-0.5
#define NEGINF (-1.0e30f)
#define PSTR   72                     // P-slab LDS row stride (fp16)
#define TSTR   136                    // O-transpose slab row stride (fp16)

typedef _Float16 f16x8 __attribute__((ext_vector_type(8)));
typedef float    f32x4 __attribute__((ext_vector_type(4)));

// ---------------------------------------------------------------------------
// Packed fragment format (validated R2/R3):
// chunk c = q*16 + o (q=c>>4, o=c&15), chunk = 8 k-consecutive f16 at outer o.
// A-operand: lane holds A[m=lane&15][k=(lane>>4)*8+j]
// B-operand: lane holds B[k=(lane>>4)*8+j][n=lane&15]
// A-pack global layout: [kt][mtg][c=lane][8], 1KB per 16x32 tile.
// ---------------------------------------------------------------------------

__global__ __launch_bounds__(256)
void pack_a(const float* __restrict__ A, _Float16* __restrict__ out,
            int M, int K) {
  const int cid = blockIdx.x * 256 + threadIdx.x;
  const int c = cid & 63;
  const int tile = cid >> 6;
  const int mtg = tile % (M >> 4);
  const int kt = tile / (M >> 4);
  const int m = c & 15, q = c >> 4;
  const float* src = A + (size_t)(mtg * 16 + m) * K + kt * 32 + q * 8;
  const float4 a = *(const float4*)src;
  const float4 b = *(const float4*)(src + 4);
  f16x8 h;
  h[0] = (_Float16)a.x; h[1] = (_Float16)a.y; h[2] = (_Float16)a.z; h[3] = (_Float16)a.w;
  h[4] = (_Float16)b.x; h[5] = (_Float16)b.y; h[6] = (_Float16)b.z; h[7] = (_Float16)b.w;
  *(f16x8*)(out + (size_t)cid * 8) = h;
}

__global__ __launch_bounds__(256)
void pack_b(const float* __restrict__ B, _Float16* __restrict__ out,
            int K, int N) {
  const int cid = blockIdx.x * 256 + threadIdx.x;
  const int c = cid & 63;
  const int tile = cid >> 6;
  const int ntg = tile % (N >> 4);
  const int kt = tile / (N >> 4);
  const int n = c & 15, q = c >> 4;
  const float* src = B + (size_t)(kt * 32 + q * 8) * N + ntg * 16 + n;
  f16x8 h;
#pragma unroll
  for (int j = 0; j < 8; ++j) h[j] = (_Float16)src[(size_t)j * N];
  *(f16x8*)(out + (size_t)cid * 8) = h;
}

__device__ __forceinline__ void gl2lds16(const void* g, void* l) {
  __builtin_amdgcn_global_load_lds((const __attribute__((address_space(1))) void*)g,
                                   (__attribute__((address_space(3))) void*)l,
                                   16, 0, 0);
}

// ---------------------------------------------------------------------------
// fp16 MFMA GEMM, BM=128, BN=128, BK=64 (two 32-k tiles per barrier).
// 256 thr = 4 waves 2x2; per barrier per wave: 32 MFMA + 16 ds_read_b128 +
// 8 global_load_lds_dwordx4. Optional split-K via blockIdx.z (C0/C1 select).
// ---------------------------------------------------------------------------
template<int BN>
__global__ __launch_bounds__(256)
void gemm_f16(const _Float16* __restrict__ Apk, const _Float16* __restrict__ Bpk,
              float* __restrict__ C0, float* __restrict__ C1,
              int M, int N, int nkt) {
  constexpr int BM = 128;
  constexpr int AT = BM / 16;          // 8
  constexpr int BT = BN / 16;          // 8
  constexpr int RT = 4;
  constexpr int CT = BN / 32;          // 4
  __shared__ _Float16 As[2 * AT * 512];
  __shared__ _Float16 Bs[2 * BT * 512];

  const int tid = threadIdx.x;
  const int lane = tid & 63;
  const int wv = tid >> 6;
  const int wr = wv & 1, wc = wv >> 1;
  const int kt0 = blockIdx.z * nkt;
  float* __restrict__ C = blockIdx.z ? C1 : C0;

  f32x4 acc[RT][CT];
#pragma unroll
  for (int i = 0; i < RT; ++i)
#pragma unroll
    for (int j = 0; j < CT; ++j) acc[i][j] = (f32x4)0.f;

  const size_t Astep = (size_t)(M >> 4) * 1024;   // bytes per 32-k tile row
  const size_t Bstep = (size_t)(N >> 4) * 1024;
  const char* Ag = (const char*)Apk + (size_t)kt0 * Astep +
                   (size_t)(blockIdx.y * AT) * 1024 + lane * 16;
  const char* Bg = (const char*)Bpk + (size_t)kt0 * Bstep +
                   (size_t)(blockIdx.x * BT) * 1024 + lane * 16;

  for (int kt2 = 0; kt2 < nkt; kt2 += 2) {
    const char* a0 = Ag + (size_t)kt2 * Astep;
    const char* b0 = Bg + (size_t)kt2 * Bstep;
#pragma unroll
    for (int t = wv; t < 2 * (AT + BT); t += 4) {
      const int half = t >= (AT + BT);
      const int tt = half ? t - (AT + BT) : t;
      if (tt < AT)
        gl2lds16(a0 + half * Astep + (size_t)tt * 1024,
                 (char*)As + (half * AT + tt) * 1024);
      else
        gl2lds16(b0 + half * Bstep + (size_t)(tt - AT) * 1024,
                 (char*)Bs + (half * BT + (tt - AT)) * 1024);
    }
    __syncthreads();

#pragma unroll
    for (int h2 = 0; h2 < 2; ++h2) {
      f16x8 af[RT], bf[CT];
#pragma unroll
      for (int i = 0; i < RT; ++i)
        af[i] = *(const f16x8*)((const char*)As + (h2 * AT + wr * RT + i) * 1024 + lane * 16);
#pragma unroll
      for (int j = 0; j < CT; ++j)
        bf[j] = *(const f16x8*)((const char*)Bs + (h2 * BT + wc * CT + j) * 1024 + lane * 16);
#pragma unroll
      for (int i = 0; i < RT; ++i)
#pragma unroll
        for (int j = 0; j < CT; ++j)
          acc[i][j] = __builtin_amdgcn_mfma_f32_16x16x32_f16(af[i], bf[j], acc[i][j], 0, 0, 0);
    }
    __syncthreads();
  }

  // C/D layout: col=lane&15, row=(lane>>4)*4+reg (validated)
  const int row0 = blockIdx.y * BM + wr * 64 + ((lane >> 4) << 2);
  const int col0 = blockIdx.x * BN + wc * (CT * 16) + (lane & 15);
#pragma unroll
  for (int i = 0; i < RT; ++i)
#pragma unroll
    for (int j = 0; j < CT; ++j) {
#pragma unroll
      for (int r = 0; r < 4; ++r)
        C[(size_t)(row0 + i * 16 + r) * N + col0 + j * 16] = acc[i][j][r];
    }
}

// ---------------------------------------------------------------------------
// split-K reduce: out = P0 + P1 (fp32, float4)
// ---------------------------------------------------------------------------
__global__ __launch_bounds__(256)
void reduce_add(const float4* __restrict__ a, const float4* __restrict__ b,
                float4* __restrict__ o, int n4) {
  for (int i = blockIdx.x * 256 + threadIdx.x; i < n4; i += gridDim.x * 256) {
    const float4 x = a[i], y = b[i];
    o[i] = make_float4(x.x + y.x, x.y + y.y, x.z + y.z, x.w + y.w);
  }
}

// ---------------------------------------------------------------------------
// RoPE tables (fp32 pipeline, matches reference fp32 math)
// ---------------------------------------------------------------------------
__global__ __launch_bounds__(64)
void rope_tables(const int* __restrict__ positions,
                 float* __restrict__ cosT, float* __restrict__ sinT) {
  const int j = threadIdx.x;
  const int p0 = blockIdx.x * 64;
  const float invf = (float)pow(1.0e6, -(double)j / 64.0);
#pragma unroll 4
  for (int i = 0; i < 64; ++i) {
    const int t = p0 + i;
    const float ang = (float)positions[t] * invf;
    cosT[t * 64 + j] = cosf(ang);
    sinT[t * 64 + j] = sinf(ang);
  }
}

// ---------------------------------------------------------------------------
// Fused RMSNorm + RoPE + fragment-pack. Block = 256 thr = 16 rows x 16
// d-groups of 8. grid(T/16, NH+NKV): y<NH -> Qpk, else Kpk.
// Writes one 16B chunk per thread, numerics identical to R3's norm_rope.
// ---------------------------------------------------------------------------
__global__ __launch_bounds__(256)
void norm_rope_pack(const float* __restrict__ qkv,
                    const float* __restrict__ qw, const float* __restrict__ kw,
                    const float* __restrict__ cosT, const float* __restrict__ sinT,
                    _Float16* __restrict__ Qpk, _Float16* __restrict__ Kpk) {
  const int bx = blockIdx.x;            // 16-row tile
  const int hh = blockIdx.y;            // 0..35
  const int tid = threadIdx.x;
  const int r = tid >> 4;               // row 0..15
  const int g = tid & 15;               // d-group (8 d's each)
  const int t = bx * 16 + r;
  const bool isq = hh < NH;
  const int srcoff = isq ? hh * D : NH * D + (hh - NH) * D;
  const float* w = isq ? qw : kw;

  const float* src = qkv + (size_t)t * QKVW + srcoff + g * 8;
  float x[8];
  *(float4*)&x[0] = *(const float4*)src;
  *(float4*)&x[4] = *(const float4*)(src + 4);

  float ss = 0.f;
#pragma unroll
  for (int j = 0; j < 8; ++j) ss += x[j] * x[j];
  ss += __shfl_xor(ss, 1);
  ss += __shfl_xor(ss, 2);
  ss += __shfl_xor(ss, 4);
  ss += __shfl_xor(ss, 8);              // lanes (r&3)*16+g: stays in wave
  const float rn = 1.0f / sqrtf(ss * (1.0f / D) + EPS);

  float nv[8];
#pragma unroll
  for (int j = 0; j < 8; ++j) nv[j] = x[j] * rn * w[g * 8 + j];

  // RoPE: pair thread g <-> g^8 (lane^8, in-wave)
  const int j64 = (g & 7) * 8;
  float c[8], s[8];
  *(float4*)&c[0] = *(const float4*)(cosT + t * 64 + j64);
  *(float4*)&c[4] = *(const float4*)(cosT + t * 64 + j64 + 4);
  *(float4*)&s[0] = *(const float4*)(sinT + t * 64 + j64);
  *(float4*)&s[4] = *(const float4*)(sinT + t * 64 + j64 + 4);

  f16x8 h8;
#pragma unroll
  for (int j = 0; j < 8; ++j) {
    const float pr = __shfl_xor(nv[j], 8);
    const float o = (g < 8) ? (nv[j] * c[j] - pr * s[j])
                            : (nv[j] * c[j] + pr * s[j]);
    h8[j] = (_Float16)o;
  }

  const int ds = g >> 2, q16 = g & 3;
  const int hl = isq ? hh : hh - NH;
  _Float16* dst = (isq ? Qpk : Kpk) +
                  ((((size_t)hl * 128 + bx) * 4 + ds) * 64 + q16 * 16 + r) * 8;
  *(f16x8*)dst = h8;
}

// ---------------------------------------------------------------------------
// V pack (B-operand of P*V): [kvh][kt64][ks2][dt8][c64][8]
// ---------------------------------------------------------------------------
__global__ __launch_bounds__(256)
void pack_v(const float* __restrict__ qkv, _Float16* __restrict__ out) {
  const int cid = blockIdx.x * 256 + threadIdx.x;   // < 2^17
  const int c = cid & 63;
  const int dt = (cid >> 6) & 7;
  const int ks = (cid >> 9) & 1;
  const int kt64 = (cid >> 10) & 31;
  const int kvh = cid >> 15;
  const int key = kt64 * 64 + ks * 32 + (c >> 4) * 8;
  const int d = dt * 16 + (c & 15);
  const float* src = qkv + (size_t)key * QKVW + (NH + NKV) * D + kvh * D + d;
  f16x8 h8;
#pragma unroll
  for (int j = 0; j < 8; ++j) h8[j] = (_Float16)src[(size_t)j * QKVW];
  *(f16x8*)(out + (size_t)cid * 8) = h8;
}

// ---------------------------------------------------------------------------
// MFMA flash attention, sliding window. grid(NH, T/64), 256 thr = 4 waves.
// Epilogue writes O directly in gemm2 A-operand packed fp16 (LDS transpose
// through the dead Ks staging region).
// ---------------------------------------------------------------------------
__global__ __launch_bounds__(256)
void attn_mfma(const _Float16* __restrict__ Qpk, const _Float16* __restrict__ Kpk,
               const _Float16* __restrict__ Vpk, _Float16* __restrict__ Ap2) {
  const int h = blockIdx.x;
  const int q0 = blockIdx.y * 64;
  const int kvh = h >> 3;
  const int tid = threadIdx.x;
  const int lane = tid & 63;
  const int wv = tid >> 6;
  const int l15 = lane & 15;
  const int l4 = lane >> 4;

  __shared__ _Float16 SM[2 * 16 * 512 + 4 * 16 * PSTR];
  _Float16* Ks = SM;                    // 16 KB staging
  _Float16* Vs = SM + 8192;             // 16 KB staging
  _Float16* Pw = SM + 16384 + wv * 16 * PSTR;

  f16x8 qf[4];
  {
    const _Float16* qb = Qpk + (size_t)(h * 128 + (q0 >> 4) + wv) * 2048 + lane * 8;
#pragma unroll
    for (int ds = 0; ds < 4; ++ds) qf[ds] = *(const f16x8*)(qb + ds * 512);
  }

  f32x4 O[8];
#pragma unroll
  for (int dt = 0; dt < 8; ++dt) O[dt] = (f32x4)0.f;
  float mrow[4], lrow[4];
#pragma unroll
  for (int r = 0; r < 4; ++r) { mrow[r] = NEGINF; lrow[r] = 0.f; }

  int kstart = q0 - (WINDOW - 1);
  if (kstart < 0) kstart = 0;
  kstart &= ~63;

  for (int kt = kstart; kt < q0 + 64; kt += 64) {
    __syncthreads();
    const _Float16* Kg = Kpk + ((size_t)kvh * 128 + (kt >> 4)) * 2048 + lane * 8;
    const _Float16* Vg = Vpk + ((size_t)kvh * 32 + (kt >> 6)) * 8192 + lane * 8;
#pragma unroll
    for (int t = wv; t < 16; t += 4) {
      gl2lds16(Kg + t * 512, (char*)Ks + t * 1024);
      gl2lds16(Vg + t * 512, (char*)Vs + t * 1024);
    }
    __syncthreads();

    // S = Q K^T
    f32x4 acc[4];
#pragma unroll
    for (int nt = 0; nt < 4; ++nt) acc[nt] = (f32x4)0.f;
#pragma unroll
    for (int ds = 0; ds < 4; ++ds) {
#pragma unroll
      for (int nt = 0; nt < 4; ++nt) {
        const f16x8 kf = *(const f16x8*)(Ks + (nt * 4 + ds) * 512 + lane * 8);
        acc[nt] = __builtin_amdgcn_mfma_f32_16x16x32_f16(qf[ds], kf, acc[nt], 0, 0, 0);
      }
    }

    const int qbase = q0 + wv * 16 + l4 * 4;
    const int kbase = kt + l15;
#pragma unroll
    for (int nt = 0; nt < 4; ++nt) {
#pragma unroll
      for (int r = 0; r < 4; ++r) {
        const int delta = (qbase + r) - (kbase + nt * 16);
        acc[nt][r] = ((unsigned)delta < WINDOW) ? acc[nt][r] * SCALE : NEGINF;
      }
    }

    float p[4][4], alpha[4];
#pragma unroll
    for (int r = 0; r < 4; ++r) {
      float mx = fmaxf(fmaxf(acc[0][r], acc[1][r]), fmaxf(acc[2][r], acc[3][r]));
      mx = fmaxf(mx, __shfl_xor(mx, 1));
      mx = fmaxf(mx, __shfl_xor(mx, 2));
      mx = fmaxf(mx, __shfl_xor(mx, 4));
      mx = fmaxf(mx, __shfl_xor(mx, 8));
      const float mt = fmaxf(mrow[r], mx);
      alpha[r] = expf(mrow[r] - mt);
      mrow[r] = mt;
      float s = 0.f;
#pragma unroll
      for (int nt = 0; nt < 4; ++nt) {
        const float pv = expf(acc[nt][r] - mt);
        p[nt][r] = pv;
        s += pv;
      }
      s += __shfl_xor(s, 1);
      s += __shfl_xor(s, 2);
      s += __shfl_xor(s, 4);
      s += __shfl_xor(s, 8);
      lrow[r] = lrow[r] * alpha[r] + s;
    }
#pragma unroll
    for (int dt = 0; dt < 8; ++dt)
#pragma unroll
      for (int r = 0; r < 4; ++r) O[dt][r] *= alpha[r];

#pragma unroll
    for (int nt = 0; nt < 4; ++nt)
#pragma unroll
      for (int r = 0; r < 4; ++r)
        Pw[(l4 * 4 + r) * PSTR + nt * 16 + l15] = (_Float16)p[nt][r];

#pragma unroll
    for (int ks = 0; ks < 2; ++ks) {
      const f16x8 pf = *(const f16x8*)(Pw + l15 * PSTR + ks * 32 + l4 * 8);
#pragma unroll
      for (int dt = 0; dt < 8; ++dt) {
        const f16x8 vf = *(const f16x8*)(Vs + (ks * 8 + dt) * 512 + lane * 8);
        O[dt] = __builtin_amdgcn_mfma_f32_16x16x32_f16(pf, vf, O[dt], 0, 0, 0);
      }
    }
  }

  // ---- epilogue: normalize, transpose via LDS, write packed A-format ----
  __syncthreads();                      // all waves done with Ks/Vs
  float inv[4];
#pragma unroll
  for (int r = 0; r < 4; ++r) inv[r] = 1.0f / lrow[r];

  _Float16* Tw = SM + wv * 16 * TSTR;   // 16 x 128, stride 136 (in dead Ks/Vs)
#pragma unroll
  for (int dt = 0; dt < 8; ++dt)
#pragma unroll
    for (int r = 0; r < 4; ++r)
      Tw[(l4 * 4 + r) * TSTR + dt * 16 + l15] = (_Float16)(O[dt][r] * inv[r]);

  // read back in A-frag order: lane -> A[m=l15][k=l4*8..+8] per 32-k tile ds
#pragma unroll
  for (int ds = 0; ds < 4; ++ds) {
    const f16x8 frag = *(const f16x8*)(Tw + l15 * TSTR + ds * 32 + l4 * 8);
    _Float16* dst = Ap2 + ((size_t)(h * 4 + ds) * 128 + (q0 >> 4) + wv) * 512 + lane * 8;
    *(f16x8*)dst = frag;
  }
}

// ---------------------------------------------------------------------------
// Launch
// ---------------------------------------------------------------------------
extern "C" void kernel_launch(void* const* d_in, const int* in_sizes, int n_in,
                              void* d_out, int out_size, void* d_ws, size_t ws_size,
                              hipStream_t stream) {
  const int*   positions = (const int*)d_in[0];
  const float* hidden    = (const float*)d_in[1];
  const float* w_qkv     = (const float*)d_in[2];
  const float* w_o       = (const float*)d_in[3];
  const float* q_norm_w  = (const float*)d_in[4];
  const float* k_norm_w  = (const float*)d_in[5];
  float* out = (float*)d_out;

  // workspace (139.5 MB, same footprint as R3)
  char* ws = (char*)d_ws;
  float* qkv  = (float*)ws;  ws += (size_t)T * QKVW * 4;          // 41.9 MB
  // old attn region 33.6 MB: [Ap2 fp16 16.8 | P0 fp32 16.8]
  _Float16* Ap2 = (_Float16*)ws;
  float* P0 = (float*)(ws + (size_t)T * ODIM * 2);
  ws += (size_t)T * ODIM * 4;
  float* cosT = (float*)ws;  ws += (size_t)T * 64 * 4;
  float* sinT = (float*)ws;  ws += (size_t)T * 64 * 4;
  _Float16* Bp1 = (_Float16*)ws; ws += (size_t)HIDDEN * QKVW * 2; // 21.0 MB
  _Float16* Bp2 = (_Float16*)ws; ws += (size_t)ODIM * HIDDEN * 2; // 16.8 MB
  // region X: Ah1 (dead after gemm1) aliased with Kpk+Vpk
  _Float16* Ah1 = (_Float16*)ws;
  _Float16* Kpk = (_Float16*)ws;
  _Float16* Vpk = Kpk + (size_t)T * NKV * D;
  ws += (size_t)T * HIDDEN * 2;                                   // 8.4 MB
  // region Y: Qpk (dead after attn) aliased with split-K partial P1
  _Float16* Qpk = (_Float16*)ws;
  float* P1 = (float*)Qpk;
  ws += (size_t)T * ODIM * 2;                                     // 16.8 MB

  // pack GEMM operands
  pack_a<<<dim3((size_t)T * HIDDEN / 8 / 256), 256, 0, stream>>>(hidden, Ah1, T, HIDDEN);
  pack_b<<<dim3((size_t)HIDDEN * QKVW / 8 / 256), 256, 0, stream>>>(w_qkv, Bp1, HIDDEN, QKVW);
  pack_b<<<dim3((size_t)ODIM * HIDDEN / 8 / 256), 256, 0, stream>>>(w_o, Bp2, ODIM, HIDDEN);

  // 1) qkv = hidden @ w_qkv (K=2048 -> nkt=64)
  gemm_f16<128><<<dim3(QKVW / 128, T / 128, 1), 256, 0, stream>>>(
      Ah1, Bp1, qkv, qkv, T, QKVW, HIDDEN / 32);

  // 2) RoPE tables + fused RMSNorm/RoPE/pack -> Qpk, Kpk
  rope_tables<<<dim3(T / 64), 64, 0, stream>>>(positions, cosT, sinT);
  norm_rope_pack<<<dim3(T / 16, NH + NKV), 256, 0, stream>>>(
      qkv, q_norm_w, k_norm_w, cosT, sinT, Qpk, Kpk);
  pack_v<<<dim3(131072 / 256), 256, 0, stream>>>(qkv, Vpk);

  // 3) MFMA flash attention -> Ap2 (packed fp16 A-operand of gemm2)
  attn_mfma<<<dim3(NH, T / 64), 256, 0, stream>>>(Qpk, Kpk, Vpk, Ap2);

  // 4) out = attn @ w_o, split-K=2 (each half K=2048 -> nkt=64), then reduce
  gemm_f16<128><<<dim3(HIDDEN / 128, T / 128, 2), 256, 0, stream>>>(
      Ap2, Bp2, P0, P1, T, HIDDEN, ODIM / 32 / 2);
  reduce_add<<<dim3(512), 256, 0, stream>>>((const float4*)P0, (const float4*)P1,
                                            (float4*)out, T * HIDDEN / 4);
}

// Round 5
// 308.678 us; speedup vs baseline: 6.6357x; 1.0624x over previous
//
#include <hip/hip_runtime.h>
#include <math.h>

// Problem constants
#define T      2048
#define HIDDEN 2048
#define NH     32
#define NKV    4
#define D      128
#define WINDOW 512
#define QKVW   ((NH + 2 * NKV) * D)   // 5120
#define ODIM   (NH * D)               // 4096
#define EPS    1e-6f
#define SCALE  0.08838834764831845f   // D^-0.5
#define PSTR   68                     // P-slab stride: row*34 banks -> 2/row, conflict-free
#define TSTR   136                    // O-transpose slab row stride (fp16)
// fold SCALE*log2(e) into packed Q; fold -MAXS*log2(e) into S-accumulator init
#define QMUL   ((float)(0.08838834764831845 * 1.4426950408889634))
#define MLOG2E 5.7707801635558536f    // 4.0 * log2(e); scores bounded by 11.3 (Cauchy-Schwarz)

typedef _Float16 f16x8 __attribute__((ext_vector_type(8)));
typedef float    f32x4 __attribute__((ext_vector_type(4)));

// ---------------------------------------------------------------------------
// Packed fragment format (validated R2-R4):
// chunk c = q*16 + o (q=c>>4, o=c&15), chunk = 8 k-consecutive f16 at outer o.
// A-operand: lane holds A[m=lane&15][k=(lane>>4)*8+j]
// B-operand: lane holds B[k=(lane>>4)*8+j][n=lane&15]
// ---------------------------------------------------------------------------

__global__ __launch_bounds__(256)
void pack_a(const float* __restrict__ A, _Float16* __restrict__ out,
            int M, int K) {
  const int cid = blockIdx.x * 256 + threadIdx.x;
  const int c = cid & 63;
  const int tile = cid >> 6;
  const int mtg = tile % (M >> 4);
  const int kt = tile / (M >> 4);
  const int m = c & 15, q = c >> 4;
  const float* src = A + (size_t)(mtg * 16 + m) * K + kt * 32 + q * 8;
  const float4 a = *(const float4*)src;
  const float4 b = *(const float4*)(src + 4);
  f16x8 h;
  h[0] = (_Float16)a.x; h[1] = (_Float16)a.y; h[2] = (_Float16)a.z; h[3] = (_Float16)a.w;
  h[4] = (_Float16)b.x; h[5] = (_Float16)b.y; h[6] = (_Float16)b.z; h[7] = (_Float16)b.w;
  *(f16x8*)(out + (size_t)cid * 8) = h;
}

__global__ __launch_bounds__(256)
void pack_b(const float* __restrict__ B, _Float16* __restrict__ out,
            int K, int N) {
  const int cid = blockIdx.x * 256 + threadIdx.x;
  const int c = cid & 63;
  const int tile = cid >> 6;
  const int ntg = tile % (N >> 4);
  const int kt = tile / (N >> 4);
  const int n = c & 15, q = c >> 4;
  const float* src = B + (size_t)(kt * 32 + q * 8) * N + ntg * 16 + n;
  f16x8 h;
#pragma unroll
  for (int j = 0; j < 8; ++j) h[j] = (_Float16)src[(size_t)j * N];
  *(f16x8*)(out + (size_t)cid * 8) = h;
}

__device__ __forceinline__ void gl2lds16(const void* g, void* l) {
  __builtin_amdgcn_global_load_lds((const __attribute__((address_space(1))) void*)g,
                                   (__attribute__((address_space(3))) void*)l,
                                   16, 0, 0);
}

// ---------------------------------------------------------------------------
// fp16 MFMA GEMM (validated R4): BM=128, BN=128, BK=64, 4 waves 2x2,
// optional split-K via blockIdx.z.
// ---------------------------------------------------------------------------
template<int BN>
__global__ __launch_bounds__(256)
void gemm_f16(const _Float16* __restrict__ Apk, const _Float16* __restrict__ Bpk,
              float* __restrict__ C0, float* __restrict__ C1,
              int M, int N, int nkt) {
  constexpr int BM = 128;
  constexpr int AT = BM / 16;
  constexpr int BT = BN / 16;
  constexpr int RT = 4;
  constexpr int CT = BN / 32;
  __shared__ _Float16 As[2 * AT * 512];
  __shared__ _Float16 Bs[2 * BT * 512];

  const int tid = threadIdx.x;
  const int lane = tid & 63;
  const int wv = tid >> 6;
  const int wr = wv & 1, wc = wv >> 1;
  const int kt0 = blockIdx.z * nkt;
  float* __restrict__ C = blockIdx.z ? C1 : C0;

  f32x4 acc[RT][CT];
#pragma unroll
  for (int i = 0; i < RT; ++i)
#pragma unroll
    for (int j = 0; j < CT; ++j) acc[i][j] = (f32x4)0.f;

  const size_t Astep = (size_t)(M >> 4) * 1024;
  const size_t Bstep = (size_t)(N >> 4) * 1024;
  const char* Ag = (const char*)Apk + (size_t)kt0 * Astep +
                   (size_t)(blockIdx.y * AT) * 1024 + lane * 16;
  const char* Bg = (const char*)Bpk + (size_t)kt0 * Bstep +
                   (size_t)(blockIdx.x * BT) * 1024 + lane * 16;

  for (int kt2 = 0; kt2 < nkt; kt2 += 2) {
    const char* a0 = Ag + (size_t)kt2 * Astep;
    const char* b0 = Bg + (size_t)kt2 * Bstep;
#pragma unroll
    for (int t = wv; t < 2 * (AT + BT); t += 4) {
      const int half = t >= (AT + BT);
      const int tt = half ? t - (AT + BT) : t;
      if (tt < AT)
        gl2lds16(a0 + half * Astep + (size_t)tt * 1024,
                 (char*)As + (half * AT + tt) * 1024);
      else
        gl2lds16(b0 + half * Bstep + (size_t)(tt - AT) * 1024,
                 (char*)Bs + (half * BT + (tt - AT)) * 1024);
    }
    __syncthreads();

#pragma unroll
    for (int h2 = 0; h2 < 2; ++h2) {
      f16x8 af[RT], bf[CT];
#pragma unroll
      for (int i = 0; i < RT; ++i)
        af[i] = *(const f16x8*)((const char*)As + (h2 * AT + wr * RT + i) * 1024 + lane * 16);
#pragma unroll
      for (int j = 0; j < CT; ++j)
        bf[j] = *(const f16x8*)((const char*)Bs + (h2 * BT + wc * CT + j) * 1024 + lane * 16);
#pragma unroll
      for (int i = 0; i < RT; ++i)
#pragma unroll
        for (int j = 0; j < CT; ++j)
          acc[i][j] = __builtin_amdgcn_mfma_f32_16x16x32_f16(af[i], bf[j], acc[i][j], 0, 0, 0);
    }
    __syncthreads();
  }

  const int row0 = blockIdx.y * BM + wr * 64 + ((lane >> 4) << 2);
  const int col0 = blockIdx.x * BN + wc * (CT * 16) + (lane & 15);
#pragma unroll
  for (int i = 0; i < RT; ++i)
#pragma unroll
    for (int j = 0; j < CT; ++j) {
#pragma unroll
      for (int r = 0; r < 4; ++r)
        C[(size_t)(row0 + i * 16 + r) * N + col0 + j * 16] = acc[i][j][r];
    }
}

__global__ __launch_bounds__(256)
void reduce_add(const float4* __restrict__ a, const float4* __restrict__ b,
                float4* __restrict__ o, int n4) {
  for (int i = blockIdx.x * 256 + threadIdx.x; i < n4; i += gridDim.x * 256) {
    const float4 x = a[i], y = b[i];
    o[i] = make_float4(x.x + y.x, x.y + y.y, x.z + y.z, x.w + y.w);
  }
}

__global__ __launch_bounds__(64)
void rope_tables(const int* __restrict__ positions,
                 float* __restrict__ cosT, float* __restrict__ sinT) {
  const int j = threadIdx.x;
  const int p0 = blockIdx.x * 64;
  const float invf = (float)pow(1.0e6, -(double)j / 64.0);
#pragma unroll 4
  for (int i = 0; i < 64; ++i) {
    const int t = p0 + i;
    const float ang = (float)positions[t] * invf;
    cosT[t * 64 + j] = cosf(ang);
    sinT[t * 64 + j] = sinf(ang);
  }
}

// ---------------------------------------------------------------------------
// Fused RMSNorm + RoPE + fragment-pack (validated R4). Q additionally scaled
// by SCALE*log2e so attention's S-MFMA directly yields log2-domain scores.
// ---------------------------------------------------------------------------
__global__ __launch_bounds__(256)
void norm_rope_pack(const float* __restrict__ qkv,
                    const float* __restrict__ qw, const float* __restrict__ kw,
                    const float* __restrict__ cosT, const float* __restrict__ sinT,
                    _Float16* __restrict__ Qpk, _Float16* __restrict__ Kpk) {
  const int bx = blockIdx.x;
  const int hh = blockIdx.y;
  const int tid = threadIdx.x;
  const int r = tid >> 4;
  const int g = tid & 15;
  const int t = bx * 16 + r;
  const bool isq = hh < NH;
  const int srcoff = isq ? hh * D : NH * D + (hh - NH) * D;
  const float* w = isq ? qw : kw;
  const float omul = isq ? QMUL : 1.0f;

  const float* src = qkv + (size_t)t * QKVW + srcoff + g * 8;
  float x[8];
  *(float4*)&x[0] = *(const float4*)src;
  *(float4*)&x[4] = *(const float4*)(src + 4);

  float ss = 0.f;
#pragma unroll
  for (int j = 0; j < 8; ++j) ss += x[j] * x[j];
  ss += __shfl_xor(ss, 1);
  ss += __shfl_xor(ss, 2);
  ss += __shfl_xor(ss, 4);
  ss += __shfl_xor(ss, 8);
  const float rn = 1.0f / sqrtf(ss * (1.0f / D) + EPS);

  float nv[8];
#pragma unroll
  for (int j = 0; j < 8; ++j) nv[j] = x[j] * rn * w[g * 8 + j];

  const int j64 = (g & 7) * 8;
  float c[8], s[8];
  *(float4*)&c[0] = *(const float4*)(cosT + t * 64 + j64);
  *(float4*)&c[4] = *(const float4*)(cosT + t * 64 + j64 + 4);
  *(float4*)&s[0] = *(const float4*)(sinT + t * 64 + j64);
  *(float4*)&s[4] = *(const float4*)(sinT + t * 64 + j64 + 4);

  f16x8 h8;
#pragma unroll
  for (int j = 0; j < 8; ++j) {
    const float pr = __shfl_xor(nv[j], 8);
    const float o = (g < 8) ? (nv[j] * c[j] - pr * s[j])
                            : (nv[j] * c[j] + pr * s[j]);
    h8[j] = (_Float16)(o * omul);
  }

  const int ds = g >> 2, q16 = g & 3;
  const int hl = isq ? hh : hh - NH;
  _Float16* dst = (isq ? Qpk : Kpk) +
                  ((((size_t)hl * 128 + bx) * 4 + ds) * 64 + q16 * 16 + r) * 8;
  *(f16x8*)dst = h8;
}

__global__ __launch_bounds__(256)
void pack_v(const float* __restrict__ qkv, _Float16* __restrict__ out) {
  const int cid = blockIdx.x * 256 + threadIdx.x;
  const int c = cid & 63;
  const int dt = (cid >> 6) & 7;
  const int ks = (cid >> 9) & 1;
  const int kt64 = (cid >> 10) & 31;
  const int kvh = cid >> 15;
  const int key = kt64 * 64 + ks * 32 + (c >> 4) * 8;
  const int d = dt * 16 + (c & 15);
  const float* src = qkv + (size_t)key * QKVW + (NH + NKV) * D + kvh * D + d;
  f16x8 h8;
#pragma unroll
  for (int j = 0; j < 8; ++j) h8[j] = (_Float16)src[(size_t)j * QKVW];
  *(f16x8*)(out + (size_t)cid * 8) = h8;
}

// ---------------------------------------------------------------------------
// MFMA flash attention, static-max softmax. grid(NH, T/128), 4 waves.
// Wave owns 32 queries (two 16-q halves A/B); 64-key tiles staged to LDS.
// Q pre-scaled by SCALE*log2e; S-acc init = -4*log2e => p = exp2(acc) = 
// exp(score-4). Scores provably bounded by 11.3 => p <= 1480, fp16-safe.
// Row-sums l via ones-column MFMA. Masked keys: p = 0 (no -inf machinery).
// ---------------------------------------------------------------------------
__global__ __launch_bounds__(256)
void attn_mfma(const _Float16* __restrict__ Qpk, const _Float16* __restrict__ Kpk,
               const _Float16* __restrict__ Vpk, _Float16* __restrict__ Ap2) {
  const int h = blockIdx.x;
  const int q0 = blockIdx.y * 128;
  const int kvh = h >> 3;
  const int tid = threadIdx.x;
  const int lane = tid & 63;
  const int wv = tid >> 6;
  const int l15 = lane & 15;
  const int l4 = lane >> 4;

  __shared__ _Float16 SM[8192 + 8192 + 4 * 32 * PSTR];   // 50176 B
  _Float16* Ks = SM;
  _Float16* Vs = SM + 8192;
  _Float16* Pw = SM + 16384 + wv * 32 * PSTR;

  // two 16-query A-frag sets per wave
  f16x8 qfA[4], qfB[4];
  {
    const _Float16* qa = Qpk + ((size_t)h * 128 + (q0 >> 4) + wv * 2) * 2048 + lane * 8;
#pragma unroll
    for (int ds = 0; ds < 4; ++ds) {
      qfA[ds] = *(const f16x8*)(qa + ds * 512);
      qfB[ds] = *(const f16x8*)(qa + 2048 + ds * 512);
    }
  }

  f16x8 ones;
#pragma unroll
  for (int j = 0; j < 8; ++j) ones[j] = (_Float16)1.0f;

  f32x4 OA[8], OB[8];
#pragma unroll
  for (int dt = 0; dt < 8; ++dt) { OA[dt] = (f32x4)0.f; OB[dt] = (f32x4)0.f; }
  f32x4 LA = (f32x4)0.f, LB = (f32x4)0.f;

  int kstart = q0 - (WINDOW - 1);
  if (kstart < 0) kstart = 0;
  kstart &= ~63;

  for (int kt = kstart; kt < q0 + 128; kt += 64) {
    __syncthreads();
    const _Float16* Kg = Kpk + ((size_t)kvh * 128 + (kt >> 4)) * 2048 + lane * 8;
    const _Float16* Vg = Vpk + ((size_t)kvh * 32 + (kt >> 6)) * 8192 + lane * 8;
#pragma unroll
    for (int t = wv; t < 16; t += 4) {
      gl2lds16(Kg + t * 512, (char*)Ks + t * 1024);
      gl2lds16(Vg + t * 512, (char*)Vs + t * 1024);
    }
    __syncthreads();

    // S = Q K^T for both query halves; each kf read feeds 2 MFMAs
    f32x4 sA[4], sB[4];
#pragma unroll
    for (int nt = 0; nt < 4; ++nt) { sA[nt] = (f32x4)(-MLOG2E); sB[nt] = (f32x4)(-MLOG2E); }
#pragma unroll
    for (int ds = 0; ds < 4; ++ds) {
#pragma unroll
      for (int nt = 0; nt < 4; ++nt) {
        const f16x8 kf = *(const f16x8*)(Ks + (nt * 4 + ds) * 512 + lane * 8);
        sA[nt] = __builtin_amdgcn_mfma_f32_16x16x32_f16(qfA[ds], kf, sA[nt], 0, 0, 0);
        sB[nt] = __builtin_amdgcn_mfma_f32_16x16x32_f16(qfB[ds], kf, sB[nt], 0, 0, 0);
      }
    }

    // p = exp2(s), zero outside window; write both P halves (conflict-free)
    const int qbA = q0 + wv * 32 + l4 * 4;
    const int kb = kt + l15;
#pragma unroll
    for (int nt = 0; nt < 4; ++nt) {
      const int kidx = kb + nt * 16;
#pragma unroll
      for (int r = 0; r < 4; ++r) {
        float pA = __builtin_amdgcn_exp2f(sA[nt][r]);
        float pB = __builtin_amdgcn_exp2f(sB[nt][r]);
        pA = ((unsigned)(qbA + r - kidx) < WINDOW) ? pA : 0.f;
        pB = ((unsigned)(qbA + 16 + r - kidx) < WINDOW) ? pB : 0.f;
        Pw[(l4 * 4 + r) * PSTR + nt * 16 + l15] = (_Float16)pA;
        Pw[(16 + l4 * 4 + r) * PSTR + nt * 16 + l15] = (_Float16)pB;
      }
    }
    // wave-private slab: in-wave DS ordering + lgkmcnt make reads safe

    // O += P V ; L += P 1  (each vf read feeds 2 MFMAs)
#pragma unroll
    for (int ks = 0; ks < 2; ++ks) {
      const f16x8 pfA = *(const f16x8*)(Pw + l15 * PSTR + ks * 32 + l4 * 8);
      const f16x8 pfB = *(const f16x8*)(Pw + (16 + l15) * PSTR + ks * 32 + l4 * 8);
      LA = __builtin_amdgcn_mfma_f32_16x16x32_f16(pfA, ones, LA, 0, 0, 0);
      LB = __builtin_amdgcn_mfma_f32_16x16x32_f16(pfB, ones, LB, 0, 0, 0);
#pragma unroll
      for (int dt = 0; dt < 8; ++dt) {
        const f16x8 vf = *(const f16x8*)(Vs + (ks * 8 + dt) * 512 + lane * 8);
        OA[dt] = __builtin_amdgcn_mfma_f32_16x16x32_f16(pfA, vf, OA[dt], 0, 0, 0);
        OB[dt] = __builtin_amdgcn_mfma_f32_16x16x32_f16(pfB, vf, OB[dt], 0, 0, 0);
      }
    }
  }

  // ---- epilogue: normalize, transpose via LDS, write gemm2 A-operand ----
  __syncthreads();                      // all waves done with Ks/Vs
  _Float16* Tw = SM + wv * 16 * TSTR;   // per-wave 16x128 slab in dead Ks
#pragma unroll
  for (int half = 0; half < 2; ++half) {
    const f32x4* O = half ? OB : OA;
    const f32x4  L = half ? LB : LA;
    float inv[4];
#pragma unroll
    for (int r = 0; r < 4; ++r) inv[r] = 1.0f / L[r];
#pragma unroll
    for (int dt = 0; dt < 8; ++dt)
#pragma unroll
      for (int r = 0; r < 4; ++r)
        Tw[(l4 * 4 + r) * TSTR + dt * 16 + l15] = (_Float16)(O[dt][r] * inv[r]);
    const int qt = (q0 >> 4) + wv * 2 + half;
#pragma unroll
    for (int ds = 0; ds < 4; ++ds) {
      const f16x8 frag = *(const f16x8*)(Tw + l15 * TSTR + ds * 32 + l4 * 8);
      *(f16x8*)(Ap2 + ((size_t)(h * 4 + ds) * 128 + qt) * 512 + lane * 8) = frag;
    }
  }
}

// ---------------------------------------------------------------------------
// Launch
// ---------------------------------------------------------------------------
extern "C" void kernel_launch(void* const* d_in, const int* in_sizes, int n_in,
                              void* d_out, int out_size, void* d_ws, size_t ws_size,
                              hipStream_t stream) {
  const int*   positions = (const int*)d_in[0];
  const float* hidden    = (const float*)d_in[1];
  const float* w_qkv     = (const float*)d_in[2];
  const float* w_o       = (const float*)d_in[3];
  const float* q_norm_w  = (const float*)d_in[4];
  const float* k_norm_w  = (const float*)d_in[5];
  float* out = (float*)d_out;

  // workspace (139.5 MB, unchanged layout from R4)
  char* ws = (char*)d_ws;
  float* qkv  = (float*)ws;  ws += (size_t)T * QKVW * 4;
  _Float16* Ap2 = (_Float16*)ws;
  float* P0 = (float*)(ws + (size_t)T * ODIM * 2);
  ws += (size_t)T * ODIM * 4;
  float* cosT = (float*)ws;  ws += (size_t)T * 64 * 4;
  float* sinT = (float*)ws;  ws += (size_t)T * 64 * 4;
  _Float16* Bp1 = (_Float16*)ws; ws += (size_t)HIDDEN * QKVW * 2;
  _Float16* Bp2 = (_Float16*)ws; ws += (size_t)ODIM * HIDDEN * 2;
  _Float16* Ah1 = (_Float16*)ws;
  _Float16* Kpk = (_Float16*)ws;
  _Float16* Vpk = Kpk + (size_t)T * NKV * D;
  ws += (size_t)T * HIDDEN * 2;
  _Float16* Qpk = (_Float16*)ws;
  float* P1 = (float*)Qpk;
  ws += (size_t)T * ODIM * 2;

  pack_a<<<dim3((size_t)T * HIDDEN / 8 / 256), 256, 0, stream>>>(hidden, Ah1, T, HIDDEN);
  pack_b<<<dim3((size_t)HIDDEN * QKVW / 8 / 256), 256, 0, stream>>>(w_qkv, Bp1, HIDDEN, QKVW);
  pack_b<<<dim3((size_t)ODIM * HIDDEN / 8 / 256), 256, 0, stream>>>(w_o, Bp2, ODIM, HIDDEN);

  gemm_f16<128><<<dim3(QKVW / 128, T / 128, 1), 256, 0, stream>>>(
      Ah1, Bp1, qkv, qkv, T, QKVW, HIDDEN / 32);

  rope_tables<<<dim3(T / 64), 64, 0, stream>>>(positions, cosT, sinT);
  norm_rope_pack<<<dim3(T / 16, NH + NKV), 256, 0, stream>>>(
      qkv, q_norm_w, k_norm_w, cosT, sinT, Qpk, Kpk);
  pack_v<<<dim3(131072 / 256), 256, 0, stream>>>(qkv, Vpk);

  attn_mfma<<<dim3(NH, T / 128), 256, 0, stream>>>(Qpk, Kpk, Vpk, Ap2);

  gemm_f16<128><<<dim3(HIDDEN / 128, T / 128, 2), 256, 0, stream>>>(
      Ap2, Bp2, P0, P1, T, HIDDEN, ODIM / 32 / 2);
  reduce_add<<<dim3(512), 256, 0, stream>>>((const float4*)P0, (const float4*)P1,
                                            (float4*)out, T * HIDDEN / 4);
}